// Round 9
// baseline (233.082 us; speedup 1.0000x reference)
//
#include <hip/hip_runtime.h>
#include <hip/hip_bf16.h>

#define B_ 32
#define T_ 256
#define D_ 64
#define H_ 128
#define G_ 384   // 3*H

typedef _Float16 half8 __attribute__((ext_vector_type(8)));
typedef _Float16 half4v __attribute__((ext_vector_type(4)));
typedef float float4v __attribute__((ext_vector_type(4)));

// Fast gate functions on PRE-SCALED inputs (log2e folded into weights/biases):
// s = log2e * x          -> sigmoid(x) = 1/(1+2^-s)
// t = 2*log2e * x        -> tanh(x)    = 1 - 2/(1+2^t)
__device__ __forceinline__ float fsigmoid2(float s){
  return __builtin_amdgcn_rcpf(1.0f + __builtin_amdgcn_exp2f(-s));
}
__device__ __forceinline__ float ftanh2(float t){
  return 1.0f - 2.0f*__builtin_amdgcn_rcpf(1.0f + __builtin_amdgcn_exp2f(t));
}
#define LOG2E  1.442695041f
#define LOG2E2 2.885390082f

// NOTE (R5-R7 post-mortem): inputs/outputs are f32. bf16 misread was the NaN bug.
//
// Structure ledger (measured):
//  - v10 (R10): 4-wave 1-BAR chained-MFMA = 1241 cyc/step (132.4 us).
//  - v11-v15 (R12-R16): fdot2 line closed (allocator remat/spill; best 139.4).
//  - v16 (R17): rcp/exp2 gates + log2e prefold = 1105 cyc/step (117.9 us).
//  - v17 (R18): 8-wave N-split, 2 waves/SIMD = ~990 cyc/step (105.7 us).
//  - v18 (R19): depth-2 chains + setprio + waves_per_eu(2,2) = ~967 cyc/step
//    (103.1 us, VGPR 88). Budget: 466 MFMA pipe (96 MFMA/CU/step, invariant)
//    + ~145 ds_read + ~110 extract/adds/gates + ~80 write/BAR + skew.
//  - v19 (R20, this): depth-1 12-chain split; gi/bn seeded INTO the MFMA
//    C-input (cvts+seeds hide under ds_read wait; kills 4 serial post-MFMA
//    adds); h-combine via single fma. Predicted -45..-60 cyc/step.
//    If <2 us gain: structural ceiling (~850 cyc) declared.
#define BAR() do{ asm volatile("s_waitcnt lgkmcnt(0)" ::: "memory"); \
                  __builtin_amdgcn_s_barrier(); \
                  asm volatile("" ::: "memory"); } while(0)

// wcol[b,j] = column sums of the row-normalized adjacency (R1 derivation):
// adj_raw[i,j] = p_i p_j sim_ij + I; rs_i = 1 + p_i*sum_j p_j sim_ij;
// wcol_j = p_j * sum_i p_i sim_ij / rs_i + 1/rs_j  (sim symmetric).
__global__ void __launch_bounds__(256) adj_k(const float* mm, const float* E,
                                             float* wcol){
  int b = blockIdx.x;
  int tid = threadIdx.x;
  int d = tid & 63, q = tid >> 6;
  __shared__ float spp[4][64];
  __shared__ float sp[64];
  __shared__ float sE[64*129];
  __shared__ float ssim[64*65];
  __shared__ float srs[64];
  float p = 0.0f;
  for (int t = q*64; t < q*64+64; t++) p += 1.0f - mm[(b*T_ + t)*D_ + d];
  spp[q][d] = p;
  for (int i = tid; i < D_*H_; i += 256){ int r = i >> 7, c = i & 127; sE[r*129+c] = E[i]; }
  __syncthreads();
  if (tid < 64) sp[tid] = (spp[0][tid]+spp[1][tid]+spp[2][tid]+spp[3][tid]) * (1.0f/T_);
  __syncthreads();
  float rowE[128];
  #pragma unroll
  for (int k = 0; k < 128; k++) rowE[k] = sE[d*129+k];
  for (int i = q*16; i < q*16+16; i++){
    float s = 0.0f;
    #pragma unroll
    for (int k = 0; k < 128; k++) s += rowE[k]*sE[i*129+k];
    ssim[d*65+i] = fmaxf(s, 0.0f);
  }
  __syncthreads();
  if (tid < 64){
    float rs = 0.0f;
    for (int j = 0; j < 64; j++) rs += sp[j]*ssim[tid*65+j];
    srs[tid] = fmaxf(sp[tid]*rs + 1.0f, 1e-6f);
  }
  __syncthreads();
  if (tid < 64){
    float s = 0.0f;
    for (int i = 0; i < 64; i++) s += sp[i]*ssim[tid*65+i]/srs[i];
    wcol[b*64 + tid] = sp[tid]*s + 1.0f/srs[tid];
  }
}

// gi_k v6: gi3 f16; E staged into LDS f16 (pitch 132); Phase-B weights/biases
// pre-scaled by LOG2E (r,z rows) / LOG2E2 (n rows) for exp2 gates.
// Phase A: vr[32t][128h] = (x*(1-mm)*wcol/64)[32t][64d] x E[64d][128h] + time-enc
// Phase B: gi[32t][384g] = vr x (sc*W_ih)^T + sc*(bih + bhh[r,z]); gi3 [b][g][t].
#define AVP 72
#define VRP 136
#define SEP 132
__global__ void __launch_bounds__(512,1) gi_k(const float* x, const float* mm,
                                              const float* vt, const float* E,
                                              const float* wih, const float* bih,
                                              const float* bhh, const float* wcol,
                                              _Float16* gi3){
  int bid = blockIdx.x;
  int b = bid >> 3, t0 = (bid & 7)*32;
  int tid = threadIdx.x;
  int w = tid >> 6, l = tid & 63;
  int lq = l >> 4, lm = l & 15;

  __shared__ __align__(16) _Float16 av[32*AVP];
  __shared__ __align__(16) _Float16 vrA[32*VRP];
  __shared__ __align__(16) _Float16 sEl[64*SEP];
  __shared__ float sVt[32];

  // stage av[t][d] = x*(1-mm)*wcol/64  (f32 in, f16 out)
  {
    int i = tid*4, t = i >> 6, d4 = i & 63;
    long src = (long)(b*T_ + t0 + t)*D_ + d4;
    float4 xv = *(const float4*)&x[src];
    float4 mv = *(const float4*)&mm[src];
    float4 wv = *(const float4*)&wcol[b*D_ + d4];
    half4v h;
    h[0]=(_Float16)(xv.x*(1.0f-mv.x)*wv.x*(1.0f/64));
    h[1]=(_Float16)(xv.y*(1.0f-mv.y)*wv.y*(1.0f/64));
    h[2]=(_Float16)(xv.z*(1.0f-mv.z)*wv.z*(1.0f/64));
    h[3]=(_Float16)(xv.w*(1.0f-mv.w)*wv.w*(1.0f/64));
    *(half4v*)&av[t*AVP + d4] = h;
  }
  // stage E -> LDS f16, coalesced
  {
    int r = tid >> 3, c0 = (tid & 7)*16;
    #pragma unroll
    for (int g = 0; g < 4; g++){
      float4 v = *(const float4*)&E[r*H_ + c0 + g*4];
      half4v h;
      h[0]=(_Float16)v.x; h[1]=(_Float16)v.y; h[2]=(_Float16)v.z; h[3]=(_Float16)v.w;
      *(half4v*)&sEl[r*SEP + c0 + g*4] = h;
    }
  }
  if (tid < 32) sVt[tid] = vt[b*T_ + t0 + tid];
  __syncthreads();

  // Phase A B-frags: B[k=d][n] = E[d][16w+n]  (gather from LDS)
  half8 bE[2];
  #pragma unroll
  for (int kc = 0; kc < 2; kc++){
    half8 f;
    #pragma unroll
    for (int jj = 0; jj < 8; jj++)
      f[jj] = sEl[(kc*32 + lq*8 + jj)*SEP + 16*w + lm];
    bE[kc] = f;
  }

  float4v accA[2] = {{0,0,0,0},{0,0,0,0}};
  #pragma unroll
  for (int kc = 0; kc < 2; kc++){
    #pragma unroll
    for (int mt = 0; mt < 2; mt++){
      half8 a = *(const half8*)&av[(mt*16+lm)*AVP + kc*32 + lq*8];
      accA[mt] = __builtin_amdgcn_mfma_f32_16x16x32_f16(a, bE[kc], accA[mt], 0,0,0);
    }
  }
  {
    int h = 16*w + lm;
    float fr = __expf(-(float)(h & 63) * 0.14391157f);   // ln(1e4)/64
    #pragma unroll
    for (int mt = 0; mt < 2; mt++){
      #pragma unroll
      for (int r = 0; r < 4; r++){
        int tl = mt*16 + lq*4 + r;
        float ang = sVt[tl] * fr;
        float e = (h < 64) ? __sinf(ang) : __cosf(ang);
        vrA[tl*VRP + h] = (_Float16)(accA[mt][r] + e);
      }
    }
  }
  __syncthreads();

  // Phase B: wave owns N-tiles 3w..3w+2; weights/bias pre-scaled for exp2 gates
  half8 bW[3][4]; float biW[3];
  #pragma unroll
  for (int q = 0; q < 3; q++){
    int g = 16*(3*w + q) + lm;
    float sc = (g < 2*H_) ? LOG2E : LOG2E2;
    biW[q] = (bih[g] + (g < 2*H_ ? bhh[g] : 0.0f)) * sc;  // fold b_hh for r,z
    #pragma unroll
    for (int kc = 0; kc < 4; kc++){
      const float* src = &wih[(long)g*H_ + kc*32 + lq*8];
      float4 x0 = *(const float4*)src;
      float4 x1 = *(const float4*)(src+4);
      half8 f;
      f[0]=(_Float16)(x0.x*sc); f[1]=(_Float16)(x0.y*sc); f[2]=(_Float16)(x0.z*sc); f[3]=(_Float16)(x0.w*sc);
      f[4]=(_Float16)(x1.x*sc); f[5]=(_Float16)(x1.y*sc); f[6]=(_Float16)(x1.z*sc); f[7]=(_Float16)(x1.w*sc);
      bW[q][kc] = f;
    }
  }
  float4v cB[2][3];
  #pragma unroll
  for (int mt = 0; mt < 2; mt++)
    #pragma unroll
    for (int q = 0; q < 3; q++) cB[mt][q] = (float4v){0,0,0,0};
  #pragma unroll
  for (int kc = 0; kc < 4; kc++){
    #pragma unroll
    for (int mt = 0; mt < 2; mt++){
      half8 a = *(const half8*)&vrA[(mt*16+lm)*VRP + kc*32 + lq*8];
      #pragma unroll
      for (int q = 0; q < 3; q++)
        cB[mt][q] = __builtin_amdgcn_mfma_f32_16x16x32_f16(a, bW[q][kc], cB[mt][q], 0,0,0);
    }
  }
  #pragma unroll
  for (int mt = 0; mt < 2; mt++){
    #pragma unroll
    for (int q = 0; q < 3; q++){
      int g = 16*(3*w + q) + lm;
      int tb = t0 + mt*16 + lq*4;
      half4v hv;
      hv[0]=(_Float16)(cB[mt][q][0] + biW[q]); hv[1]=(_Float16)(cB[mt][q][1] + biW[q]);
      hv[2]=(_Float16)(cB[mt][q][2] + biW[q]); hv[3]=(_Float16)(cB[mt][q][3] + biW[q]);
      *(half4v*)&gi3[((long)(b*G_ + g))*T_ + tb] = hv;
    }
  }
}

// Sequential GRU v19 (R20): 8-wave N-split, 12 INDEPENDENT depth-1 MFMA
// chains with SEEDED C-inputs. Wave w owns gates j in [16w,16w+16); per
// gate-part (r,z,n) 4 parallel chains (one per k-chunk); chain-a of r/z is
// seeded with the gi value, chain-a of n with bn_ — the cvt+seed movs hide
// under the ds_read wait, removing 4 serial post-MFMA adds. Sum = 2-level
// VALU tree. n-arg = fma(r, sumN, gi_n); h = fma(z, h-n, n). setprio(1)
// around MFMA cluster; waves_per_eu(2,2) truthful clamp. One LDS-only BAR
// per step, hb[2] f16 ping-pong, named A/B gi prefetch regs.
__global__ void __attribute__((amdgpu_waves_per_eu(2, 2)))
__launch_bounds__(512) gru_k(const _Float16* gi3, const float* whh,
                             const float* bhh, const int* lengths,
                             float* out){
  int b = blockIdx.x;
  int tid = threadIdx.x;
  int w = tid >> 6, l = tid & 63;
  int lq = l >> 4;
  int j = 16*w + (l & 15);       // gate dim owned (valid for all lanes)
  bool gate = (l < 16);
  int len = lengths[b];

  __shared__ __align__(16) _Float16 hb[2][H_];

  // B-frags: q=0 r, 1 z, 2 n ; B[k][n] = sc*W_hh[q*H + 16w + n][k]
  half8 bfrag[3][4];
  #pragma unroll
  for (int q = 0; q < 3; q++){
    int row = q*H_ + 16*w + (l & 15);
    float sc = (q == 2) ? LOG2E2 : LOG2E;
    #pragma unroll
    for (int kc = 0; kc < 4; kc++){
      const float* src = &whh[(long)row*H_ + kc*32 + lq*8];
      float4 x0 = *(const float4*)src;
      float4 x1 = *(const float4*)(src+4);
      half8 f;
      f[0]=(_Float16)(x0.x*sc); f[1]=(_Float16)(x0.y*sc); f[2]=(_Float16)(x0.z*sc); f[3]=(_Float16)(x0.w*sc);
      f[4]=(_Float16)(x1.x*sc); f[5]=(_Float16)(x1.y*sc); f[6]=(_Float16)(x1.z*sc); f[7]=(_Float16)(x1.w*sc);
      bfrag[q][kc] = f;
    }
  }
  float bn_ = bhh[2*H_ + j] * LOG2E2;
  const _Float16* pr = gi3 + ((long)b*G_ + j)*T_;
  const _Float16* pz = pr + (long)H_*T_;
  const _Float16* pn = pr + (long)2*H_*T_;

  if (tid < H_){ hb[0][tid] = (_Float16)0.0f; hb[1][tid] = (_Float16)0.0f; }

  // gi prefetch: named double-buffer registers, static indexing only
  half8 prA, pzA, pnA, prB, pzB, pnB;
  prA = *(const half8*)pr; pzA = *(const half8*)pz; pnA = *(const half8*)pn;
  __syncthreads();   // cold path: full barrier fine

  float hval = 0.0f;

  auto substeps = [&](half8 cr, half8 cz, half8 cn, int c){
    float ho[8];
    #pragma unroll
    for (int i = 0; i < 8; i++){
      const int rp = i & 1;            // read hb[rp], write hb[rp^1]
      half8 a0v = *(const half8*)&hb[rp][ 0 + lq*8];
      half8 a1v = *(const half8*)&hb[rp][32 + lq*8];
      half8 a2v = *(const half8*)&hb[rp][64 + lq*8];
      half8 a3v = *(const half8*)&hb[rp][96 + lq*8];
      // seeds: cvt + mov issue while ds_reads are in flight
      float crf = (float)cr[i], czf = (float)cz[i], cnf = (float)cn[i];
      float4v c0a = {crf,0,0,0}, c0b = {0,0,0,0}, c0c = {0,0,0,0}, c0d = {0,0,0,0};
      float4v c1a = {czf,0,0,0}, c1b = {0,0,0,0}, c1c = {0,0,0,0}, c1d = {0,0,0,0};
      float4v c2a = {bn_,0,0,0}, c2b = {0,0,0,0}, c2c = {0,0,0,0}, c2d = {0,0,0,0};
      __builtin_amdgcn_s_setprio(1);
      c0a = __builtin_amdgcn_mfma_f32_16x16x32_f16(a0v, bfrag[0][0], c0a, 0,0,0);
      c1a = __builtin_amdgcn_mfma_f32_16x16x32_f16(a0v, bfrag[1][0], c1a, 0,0,0);
      c2a = __builtin_amdgcn_mfma_f32_16x16x32_f16(a0v, bfrag[2][0], c2a, 0,0,0);
      c0b = __builtin_amdgcn_mfma_f32_16x16x32_f16(a1v, bfrag[0][1], c0b, 0,0,0);
      c1b = __builtin_amdgcn_mfma_f32_16x16x32_f16(a1v, bfrag[1][1], c1b, 0,0,0);
      c2b = __builtin_amdgcn_mfma_f32_16x16x32_f16(a1v, bfrag[2][1], c2b, 0,0,0);
      c0c = __builtin_amdgcn_mfma_f32_16x16x32_f16(a2v, bfrag[0][2], c0c, 0,0,0);
      c1c = __builtin_amdgcn_mfma_f32_16x16x32_f16(a2v, bfrag[1][2], c1c, 0,0,0);
      c2c = __builtin_amdgcn_mfma_f32_16x16x32_f16(a2v, bfrag[2][2], c2c, 0,0,0);
      c0d = __builtin_amdgcn_mfma_f32_16x16x32_f16(a3v, bfrag[0][3], c0d, 0,0,0);
      c1d = __builtin_amdgcn_mfma_f32_16x16x32_f16(a3v, bfrag[1][3], c1d, 0,0,0);
      c2d = __builtin_amdgcn_mfma_f32_16x16x32_f16(a3v, bfrag[2][3], c2d, 0,0,0);
      __builtin_amdgcn_s_setprio(0);
      float sr = (c0a[0] + c0b[0]) + (c0c[0] + c0d[0]);   // includes gi_r
      float sz = (c1a[0] + c1b[0]) + (c1c[0] + c1d[0]);   // includes gi_z
      float sn = (c2a[0] + c2b[0]) + (c2c[0] + c2d[0]);   // includes bn_
      float r = fsigmoid2(sr);
      float z = fsigmoid2(sz);
      float n = ftanh2(__builtin_fmaf(r, sn, cnf));
      hval = __builtin_fmaf(z, hval - n, n);
      if (gate){
        hb[rp^1][j] = (_Float16)hval;
        ho[i] = (c*8 + i < len) ? hval : 0.0f;
      }
      BAR();
    }
    if (gate){
      long ob = ((long)b*T_ + c*8)*H_ + j;
      #pragma unroll
      for (int i = 0; i < 8; i++) out[ob + (long)i*H_] = ho[i];
    }
  };

  for (int c = 0; c < 32; c += 2){
    {
      int nb = (c+1)*8;
      prB = *(const half8*)(pr+nb); pzB = *(const half8*)(pz+nb); pnB = *(const half8*)(pn+nb);
    }
    substeps(prA, pzA, pnA, c);
    if (c+2 < 32){
      int nb = (c+2)*8;
      prA = *(const half8*)(pr+nb); pzA = *(const half8*)(pz+nb); pnA = *(const half8*)(pn+nb);
    }
    substeps(prB, pzB, pnB, c+1);
  }
}

extern "C" void kernel_launch(void* const* d_in, const int* in_sizes, int n_in,
                              void* d_out, int out_size, void* d_ws, size_t ws_size,
                              hipStream_t stream) {
  char* base = (char*)d_ws;
  size_t off = 0;
  auto alloc = [&](size_t bytes)->void*{
    void* p = base + off; off = (off + bytes + 255) & ~(size_t)255; return p;
  };
  float*     wcol = (float*)alloc((size_t)B_*D_*4);
  _Float16*  gi3  = (_Float16*)alloc((size_t)B_*G_*T_*2);
  if (off > ws_size) return;

  const float* x   = (const float*)d_in[0];
  const float* mm  = (const float*)d_in[1];
  const float* vt  = (const float*)d_in[2];
  const int*   len = (const int*)d_in[4];
  const float* E   = (const float*)d_in[5];
  const float* wih = (const float*)d_in[6];
  const float* whh = (const float*)d_in[7];
  const float* bih = (const float*)d_in[8];
  const float* bhh = (const float*)d_in[9];

  adj_k<<<dim3(B_),dim3(256),0,stream>>>(mm, E, wcol);
  gi_k<<<dim3(256),dim3(512),0,stream>>>(x, mm, vt, E, wih, bih, bhh, wcol, gi3);
  gru_k<<<dim3(B_),dim3(512),0,stream>>>(gi3, whh, bhh, len, (float*)d_out);
}

// Round 10
// 231.593 us; speedup vs baseline: 1.0064x; 1.0064x over previous
//
#include <hip/hip_runtime.h>
#include <hip/hip_bf16.h>

#define B_ 32
#define T_ 256
#define D_ 64
#define H_ 128
#define G_ 384   // 3*H

typedef _Float16 half8 __attribute__((ext_vector_type(8)));
typedef _Float16 half4v __attribute__((ext_vector_type(4)));
typedef float float4v __attribute__((ext_vector_type(4)));

// Fast gate functions on PRE-SCALED inputs (log2e folded into weights/biases):
// s = log2e * x          -> sigmoid(x) = 1/(1+2^-s)
// t = 2*log2e * x        -> tanh(x)    = 1 - 2/(1+2^t)
__device__ __forceinline__ float fsigmoid2(float s){
  return __builtin_amdgcn_rcpf(1.0f + __builtin_amdgcn_exp2f(-s));
}
__device__ __forceinline__ float ftanh2(float t){
  return 1.0f - 2.0f*__builtin_amdgcn_rcpf(1.0f + __builtin_amdgcn_exp2f(t));
}
#define LOG2E  1.442695041f
#define LOG2E2 2.885390082f

// NOTE (R5-R7 post-mortem): inputs/outputs are f32. bf16 misread was the NaN bug.
//
// Structure ledger (measured):
//  - v10 (R10): 4-wave 1-BAR chained-MFMA = 1241 cyc/step (132.4 us).
//  - v11-v15 (R12-R16): fdot2 line closed (allocator remat/spill; best 139.4).
//  - v16 (R17): rcp/exp2 gates + log2e prefold = 1105 cyc/step (117.9 us).
//  - v17 (R18): 8-wave N-split, 2 waves/SIMD = ~990 cyc/step (105.7 us).
//  - v18 (R19): depth-2 6-chain + setprio + waves_per_eu(2,2) = ~967 cyc/step
//    (103.1 us, VGPR 88) — CHAMPION structure.
//  - v19 (R20): depth-1 12-chain + seeds = 113.0 us REGRESSION (+94 cyc/step):
//    acc-init cost scales with chain count (12 accs x 4 reg-writes/substep
//    = +48 cyc) + deeper final-sum tree. 6-chain depth-2 is the sweet spot.
//  - v20 (R21, this): v18 EXACT + costless v19 pieces only: seed a-chains'
//    C[0] with gi_r/gi_z/bn_ (same init count, kills 2-3 serial post-MFMA
//    adds) + 2-op h-combine fma(z,h-n,n). If >=102 us: structural floor
//    (466 MFMA pipe + ~275 LDS round-trip + ~120 gate chain) -> declare.
#define BAR() do{ asm volatile("s_waitcnt lgkmcnt(0)" ::: "memory"); \
                  __builtin_amdgcn_s_barrier(); \
                  asm volatile("" ::: "memory"); } while(0)

// wcol[b,j] = column sums of the row-normalized adjacency (R1 derivation):
// adj_raw[i,j] = p_i p_j sim_ij + I; rs_i = 1 + p_i*sum_j p_j sim_ij;
// wcol_j = p_j * sum_i p_i sim_ij / rs_i + 1/rs_j  (sim symmetric).
__global__ void __launch_bounds__(256) adj_k(const float* mm, const float* E,
                                             float* wcol){
  int b = blockIdx.x;
  int tid = threadIdx.x;
  int d = tid & 63, q = tid >> 6;
  __shared__ float spp[4][64];
  __shared__ float sp[64];
  __shared__ float sE[64*129];
  __shared__ float ssim[64*65];
  __shared__ float srs[64];
  float p = 0.0f;
  for (int t = q*64; t < q*64+64; t++) p += 1.0f - mm[(b*T_ + t)*D_ + d];
  spp[q][d] = p;
  for (int i = tid; i < D_*H_; i += 256){ int r = i >> 7, c = i & 127; sE[r*129+c] = E[i]; }
  __syncthreads();
  if (tid < 64) sp[tid] = (spp[0][tid]+spp[1][tid]+spp[2][tid]+spp[3][tid]) * (1.0f/T_);
  __syncthreads();
  float rowE[128];
  #pragma unroll
  for (int k = 0; k < 128; k++) rowE[k] = sE[d*129+k];
  for (int i = q*16; i < q*16+16; i++){
    float s = 0.0f;
    #pragma unroll
    for (int k = 0; k < 128; k++) s += rowE[k]*sE[i*129+k];
    ssim[d*65+i] = fmaxf(s, 0.0f);
  }
  __syncthreads();
  if (tid < 64){
    float rs = 0.0f;
    for (int j = 0; j < 64; j++) rs += sp[j]*ssim[tid*65+j];
    srs[tid] = fmaxf(sp[tid]*rs + 1.0f, 1e-6f);
  }
  __syncthreads();
  if (tid < 64){
    float s = 0.0f;
    for (int i = 0; i < 64; i++) s += sp[i]*ssim[tid*65+i]/srs[i];
    wcol[b*64 + tid] = sp[tid]*s + 1.0f/srs[tid];
  }
}

// gi_k v6: gi3 f16; E staged into LDS f16 (pitch 132); Phase-B weights/biases
// pre-scaled by LOG2E (r,z rows) / LOG2E2 (n rows) for exp2 gates.
// Phase A: vr[32t][128h] = (x*(1-mm)*wcol/64)[32t][64d] x E[64d][128h] + time-enc
// Phase B: gi[32t][384g] = vr x (sc*W_ih)^T + sc*(bih + bhh[r,z]); gi3 [b][g][t].
#define AVP 72
#define VRP 136
#define SEP 132
__global__ void __launch_bounds__(512,1) gi_k(const float* x, const float* mm,
                                              const float* vt, const float* E,
                                              const float* wih, const float* bih,
                                              const float* bhh, const float* wcol,
                                              _Float16* gi3){
  int bid = blockIdx.x;
  int b = bid >> 3, t0 = (bid & 7)*32;
  int tid = threadIdx.x;
  int w = tid >> 6, l = tid & 63;
  int lq = l >> 4, lm = l & 15;

  __shared__ __align__(16) _Float16 av[32*AVP];
  __shared__ __align__(16) _Float16 vrA[32*VRP];
  __shared__ __align__(16) _Float16 sEl[64*SEP];
  __shared__ float sVt[32];

  // stage av[t][d] = x*(1-mm)*wcol/64  (f32 in, f16 out)
  {
    int i = tid*4, t = i >> 6, d4 = i & 63;
    long src = (long)(b*T_ + t0 + t)*D_ + d4;
    float4 xv = *(const float4*)&x[src];
    float4 mv = *(const float4*)&mm[src];
    float4 wv = *(const float4*)&wcol[b*D_ + d4];
    half4v h;
    h[0]=(_Float16)(xv.x*(1.0f-mv.x)*wv.x*(1.0f/64));
    h[1]=(_Float16)(xv.y*(1.0f-mv.y)*wv.y*(1.0f/64));
    h[2]=(_Float16)(xv.z*(1.0f-mv.z)*wv.z*(1.0f/64));
    h[3]=(_Float16)(xv.w*(1.0f-mv.w)*wv.w*(1.0f/64));
    *(half4v*)&av[t*AVP + d4] = h;
  }
  // stage E -> LDS f16, coalesced
  {
    int r = tid >> 3, c0 = (tid & 7)*16;
    #pragma unroll
    for (int g = 0; g < 4; g++){
      float4 v = *(const float4*)&E[r*H_ + c0 + g*4];
      half4v h;
      h[0]=(_Float16)v.x; h[1]=(_Float16)v.y; h[2]=(_Float16)v.z; h[3]=(_Float16)v.w;
      *(half4v*)&sEl[r*SEP + c0 + g*4] = h;
    }
  }
  if (tid < 32) sVt[tid] = vt[b*T_ + t0 + tid];
  __syncthreads();

  // Phase A B-frags: B[k=d][n] = E[d][16w+n]  (gather from LDS)
  half8 bE[2];
  #pragma unroll
  for (int kc = 0; kc < 2; kc++){
    half8 f;
    #pragma unroll
    for (int jj = 0; jj < 8; jj++)
      f[jj] = sEl[(kc*32 + lq*8 + jj)*SEP + 16*w + lm];
    bE[kc] = f;
  }

  float4v accA[2] = {{0,0,0,0},{0,0,0,0}};
  #pragma unroll
  for (int kc = 0; kc < 2; kc++){
    #pragma unroll
    for (int mt = 0; mt < 2; mt++){
      half8 a = *(const half8*)&av[(mt*16+lm)*AVP + kc*32 + lq*8];
      accA[mt] = __builtin_amdgcn_mfma_f32_16x16x32_f16(a, bE[kc], accA[mt], 0,0,0);
    }
  }
  {
    int h = 16*w + lm;
    float fr = __expf(-(float)(h & 63) * 0.14391157f);   // ln(1e4)/64
    #pragma unroll
    for (int mt = 0; mt < 2; mt++){
      #pragma unroll
      for (int r = 0; r < 4; r++){
        int tl = mt*16 + lq*4 + r;
        float ang = sVt[tl] * fr;
        float e = (h < 64) ? __sinf(ang) : __cosf(ang);
        vrA[tl*VRP + h] = (_Float16)(accA[mt][r] + e);
      }
    }
  }
  __syncthreads();

  // Phase B: wave owns N-tiles 3w..3w+2; weights/bias pre-scaled for exp2 gates
  half8 bW[3][4]; float biW[3];
  #pragma unroll
  for (int q = 0; q < 3; q++){
    int g = 16*(3*w + q) + lm;
    float sc = (g < 2*H_) ? LOG2E : LOG2E2;
    biW[q] = (bih[g] + (g < 2*H_ ? bhh[g] : 0.0f)) * sc;  // fold b_hh for r,z
    #pragma unroll
    for (int kc = 0; kc < 4; kc++){
      const float* src = &wih[(long)g*H_ + kc*32 + lq*8];
      float4 x0 = *(const float4*)src;
      float4 x1 = *(const float4*)(src+4);
      half8 f;
      f[0]=(_Float16)(x0.x*sc); f[1]=(_Float16)(x0.y*sc); f[2]=(_Float16)(x0.z*sc); f[3]=(_Float16)(x0.w*sc);
      f[4]=(_Float16)(x1.x*sc); f[5]=(_Float16)(x1.y*sc); f[6]=(_Float16)(x1.z*sc); f[7]=(_Float16)(x1.w*sc);
      bW[q][kc] = f;
    }
  }
  float4v cB[2][3];
  #pragma unroll
  for (int mt = 0; mt < 2; mt++)
    #pragma unroll
    for (int q = 0; q < 3; q++) cB[mt][q] = (float4v){0,0,0,0};
  #pragma unroll
  for (int kc = 0; kc < 4; kc++){
    #pragma unroll
    for (int mt = 0; mt < 2; mt++){
      half8 a = *(const half8*)&vrA[(mt*16+lm)*VRP + kc*32 + lq*8];
      #pragma unroll
      for (int q = 0; q < 3; q++)
        cB[mt][q] = __builtin_amdgcn_mfma_f32_16x16x32_f16(a, bW[q][kc], cB[mt][q], 0,0,0);
    }
  }
  #pragma unroll
  for (int mt = 0; mt < 2; mt++){
    #pragma unroll
    for (int q = 0; q < 3; q++){
      int g = 16*(3*w + q) + lm;
      int tb = t0 + mt*16 + lq*4;
      half4v hv;
      hv[0]=(_Float16)(cB[mt][q][0] + biW[q]); hv[1]=(_Float16)(cB[mt][q][1] + biW[q]);
      hv[2]=(_Float16)(cB[mt][q][2] + biW[q]); hv[3]=(_Float16)(cB[mt][q][3] + biW[q]);
      *(half4v*)&gi3[((long)(b*G_ + g))*T_ + tb] = hv;
    }
  }
}

// Sequential GRU v20 (R21): v18 champion structure (8-wave N-split, 6 chains
// depth-2, setprio, waves_per_eu(2,2)) + costless seeding: a-chains' C[0]
// seeded with gi_r / gi_z / bn_ (replaces a zero-init mov, folds 2-3 serial
// post-MFMA adds into the accumulation) + 2-op h-combine fma(z, h-n, n).
// Gate math unconditional; LDS h-write + out guarded. One LDS-only BAR per
// step, hb[2] f16 ping-pong, named A/B gi prefetch regs.
__global__ void __attribute__((amdgpu_waves_per_eu(2, 2)))
__launch_bounds__(512) gru_k(const _Float16* gi3, const float* whh,
                             const float* bhh, const int* lengths,
                             float* out){
  int b = blockIdx.x;
  int tid = threadIdx.x;
  int w = tid >> 6, l = tid & 63;
  int lq = l >> 4;
  int j = 16*w + (l & 15);       // gate dim owned (valid for all lanes)
  bool gate = (l < 16);
  int len = lengths[b];

  __shared__ __align__(16) _Float16 hb[2][H_];

  // B-frags: q=0 r, 1 z, 2 n ; B[k][n] = sc*W_hh[q*H + 16w + n][k]
  half8 bfrag[3][4];
  #pragma unroll
  for (int q = 0; q < 3; q++){
    int row = q*H_ + 16*w + (l & 15);
    float sc = (q == 2) ? LOG2E2 : LOG2E;
    #pragma unroll
    for (int kc = 0; kc < 4; kc++){
      const float* src = &whh[(long)row*H_ + kc*32 + lq*8];
      float4 x0 = *(const float4*)src;
      float4 x1 = *(const float4*)(src+4);
      half8 f;
      f[0]=(_Float16)(x0.x*sc); f[1]=(_Float16)(x0.y*sc); f[2]=(_Float16)(x0.z*sc); f[3]=(_Float16)(x0.w*sc);
      f[4]=(_Float16)(x1.x*sc); f[5]=(_Float16)(x1.y*sc); f[6]=(_Float16)(x1.z*sc); f[7]=(_Float16)(x1.w*sc);
      bfrag[q][kc] = f;
    }
  }
  float bn_ = bhh[2*H_ + j] * LOG2E2;
  const _Float16* pr = gi3 + ((long)b*G_ + j)*T_;
  const _Float16* pz = pr + (long)H_*T_;
  const _Float16* pn = pr + (long)2*H_*T_;

  if (tid < H_){ hb[0][tid] = (_Float16)0.0f; hb[1][tid] = (_Float16)0.0f; }

  // gi prefetch: named double-buffer registers, static indexing only
  half8 prA, pzA, pnA, prB, pzB, pnB;
  prA = *(const half8*)pr; pzA = *(const half8*)pz; pnA = *(const half8*)pn;
  __syncthreads();   // cold path: full barrier fine

  float hval = 0.0f;

  auto substeps = [&](half8 cr, half8 cz, half8 cn, int c){
    float ho[8];
    #pragma unroll
    for (int i = 0; i < 8; i++){
      const int rp = i & 1;            // read hb[rp], write hb[rp^1]
      half8 a0v = *(const half8*)&hb[rp][ 0 + lq*8];
      half8 a1v = *(const half8*)&hb[rp][32 + lq*8];
      half8 a2v = *(const half8*)&hb[rp][64 + lq*8];
      half8 a3v = *(const half8*)&hb[rp][96 + lq*8];
      // seeds: cvt + mov issue while ds_reads are in flight (same init count
      // as zero-init; folds the gi/bn adds off the post-MFMA serial path)
      float crf = (float)cr[i], czf = (float)cz[i], cnf = (float)cn[i];
      float4v c0a = {crf,0,0,0}, c1a = {czf,0,0,0}, c2a = {bn_,0,0,0};
      float4v c0b = {0,0,0,0},   c1b = {0,0,0,0},   c2b = {0,0,0,0};
      __builtin_amdgcn_s_setprio(1);
      c0a = __builtin_amdgcn_mfma_f32_16x16x32_f16(a0v, bfrag[0][0], c0a, 0,0,0);
      c1a = __builtin_amdgcn_mfma_f32_16x16x32_f16(a0v, bfrag[1][0], c1a, 0,0,0);
      c2a = __builtin_amdgcn_mfma_f32_16x16x32_f16(a0v, bfrag[2][0], c2a, 0,0,0);
      c0b = __builtin_amdgcn_mfma_f32_16x16x32_f16(a2v, bfrag[0][2], c0b, 0,0,0);
      c1b = __builtin_amdgcn_mfma_f32_16x16x32_f16(a2v, bfrag[1][2], c1b, 0,0,0);
      c2b = __builtin_amdgcn_mfma_f32_16x16x32_f16(a2v, bfrag[2][2], c2b, 0,0,0);
      c0a = __builtin_amdgcn_mfma_f32_16x16x32_f16(a1v, bfrag[0][1], c0a, 0,0,0);
      c1a = __builtin_amdgcn_mfma_f32_16x16x32_f16(a1v, bfrag[1][1], c1a, 0,0,0);
      c2a = __builtin_amdgcn_mfma_f32_16x16x32_f16(a1v, bfrag[2][1], c2a, 0,0,0);
      c0b = __builtin_amdgcn_mfma_f32_16x16x32_f16(a3v, bfrag[0][3], c0b, 0,0,0);
      c1b = __builtin_amdgcn_mfma_f32_16x16x32_f16(a3v, bfrag[1][3], c1b, 0,0,0);
      c2b = __builtin_amdgcn_mfma_f32_16x16x32_f16(a3v, bfrag[2][3], c2b, 0,0,0);
      __builtin_amdgcn_s_setprio(0);
      float sr = c0a[0] + c0b[0];      // includes gi_r
      float sz = c1a[0] + c1b[0];      // includes gi_z
      float sn = c2a[0] + c2b[0];      // includes bn_
      float r = fsigmoid2(sr);
      float z = fsigmoid2(sz);
      float n = ftanh2(__builtin_fmaf(r, sn, cnf));
      hval = __builtin_fmaf(z, hval - n, n);
      if (gate){
        hb[rp^1][j] = (_Float16)hval;
        ho[i] = (c*8 + i < len) ? hval : 0.0f;
      }
      BAR();
    }
    if (gate){
      long ob = ((long)b*T_ + c*8)*H_ + j;
      #pragma unroll
      for (int i = 0; i < 8; i++) out[ob + (long)i*H_] = ho[i];
    }
  };

  for (int c = 0; c < 32; c += 2){
    {
      int nb = (c+1)*8;
      prB = *(const half8*)(pr+nb); pzB = *(const half8*)(pz+nb); pnB = *(const half8*)(pn+nb);
    }
    substeps(prA, pzA, pnA, c);
    if (c+2 < 32){
      int nb = (c+2)*8;
      prA = *(const half8*)(pr+nb); pzA = *(const half8*)(pz+nb); pnA = *(const half8*)(pn+nb);
    }
    substeps(prB, pzB, pnB, c+1);
  }
}

extern "C" void kernel_launch(void* const* d_in, const int* in_sizes, int n_in,
                              void* d_out, int out_size, void* d_ws, size_t ws_size,
                              hipStream_t stream) {
  char* base = (char*)d_ws;
  size_t off = 0;
  auto alloc = [&](size_t bytes)->void*{
    void* p = base + off; off = (off + bytes + 255) & ~(size_t)255; return p;
  };
  float*     wcol = (float*)alloc((size_t)B_*D_*4);
  _Float16*  gi3  = (_Float16*)alloc((size_t)B_*G_*T_*2);
  if (off > ws_size) return;

  const float* x   = (const float*)d_in[0];
  const float* mm  = (const float*)d_in[1];
  const float* vt  = (const float*)d_in[2];
  const int*   len = (const int*)d_in[4];
  const float* E   = (const float*)d_in[5];
  const float* wih = (const float*)d_in[6];
  const float* whh = (const float*)d_in[7];
  const float* bih = (const float*)d_in[8];
  const float* bhh = (const float*)d_in[9];

  adj_k<<<dim3(B_),dim3(256),0,stream>>>(mm, E, wcol);
  gi_k<<<dim3(256),dim3(512),0,stream>>>(x, mm, vt, E, wih, bih, bhh, wcol, gi3);
  gru_k<<<dim3(B_),dim3(512),0,stream>>>(gi3, whh, bhh, len, (float*)d_out);
}

// Round 11
// 229.087 us; speedup vs baseline: 1.0174x; 1.0109x over previous
//
#include <hip/hip_runtime.h>
#include <hip/hip_bf16.h>

#define B_ 32
#define T_ 256
#define D_ 64
#define H_ 128
#define G_ 384   // 3*H

typedef _Float16 half8 __attribute__((ext_vector_type(8)));
typedef _Float16 half4v __attribute__((ext_vector_type(4)));
typedef float float4v __attribute__((ext_vector_type(4)));

// Fast gate functions on PRE-SCALED inputs (log2e folded into weights/biases):
// s = log2e * x          -> sigmoid(x) = 1/(1+2^-s)
// t = 2*log2e * x        -> tanh(x)    = 1 - 2/(1+2^t)
__device__ __forceinline__ float fsigmoid2(float s){
  return __builtin_amdgcn_rcpf(1.0f + __builtin_amdgcn_exp2f(-s));
}
__device__ __forceinline__ float ftanh2(float t){
  return 1.0f - 2.0f*__builtin_amdgcn_rcpf(1.0f + __builtin_amdgcn_exp2f(t));
}
#define LOG2E  1.442695041f
#define LOG2E2 2.885390082f

// NOTE (R5-R7 post-mortem): inputs/outputs are f32. bf16 misread was the NaN bug.
//
// Structure ledger (measured, FINAL):
//  - v10 (R10): 4-wave 1-BAR chained-MFMA = 1241 cyc/step (132.4 us).
//  - v11-v15 (R12-R16): fdot2 line closed (allocator remat/spill; best 139.4).
//  - v16 (R17): rcp/exp2 gates + log2e prefold = 1105 cyc/step (117.9 us).
//  - v17 (R18): 8-wave N-split, 2 waves/SIMD = ~990 cyc/step (105.7 us).
//  - v18 (R19): depth-2 6-chain + setprio + waves_per_eu(2,2) = ~967 cyc/step
//    (103.1 us, VGPR 88) — CHAMPION. Budget: 466 MFMA pipe (96 MFMA/CU/step,
//    invariant) + ~145 ds_read + ~110 gate/extract + ~80 write/BAR + skew.
//  - v19 (R20): depth-1 12-chain = +94 cyc/step REGRESSION (acc-init scales
//    with chain count).
//  - v20 (R21): seeded C-inputs = +58 cyc/step REGRESSION (VALU-write ->
//    MFMA-read hazard puts cvts on the MFMA issue path; keep C-inputs
//    data-independent, fold scalars after the cluster).
//  - v21 (R22, this): v18 verbatim revert. All structural axes measured;
//    this is the floor of the design space explored.
#define BAR() do{ asm volatile("s_waitcnt lgkmcnt(0)" ::: "memory"); \
                  __builtin_amdgcn_s_barrier(); \
                  asm volatile("" ::: "memory"); } while(0)

// wcol[b,j] = column sums of the row-normalized adjacency (R1 derivation):
// adj_raw[i,j] = p_i p_j sim_ij + I; rs_i = 1 + p_i*sum_j p_j sim_ij;
// wcol_j = p_j * sum_i p_i sim_ij / rs_i + 1/rs_j  (sim symmetric).
__global__ void __launch_bounds__(256) adj_k(const float* mm, const float* E,
                                             float* wcol){
  int b = blockIdx.x;
  int tid = threadIdx.x;
  int d = tid & 63, q = tid >> 6;
  __shared__ float spp[4][64];
  __shared__ float sp[64];
  __shared__ float sE[64*129];
  __shared__ float ssim[64*65];
  __shared__ float srs[64];
  float p = 0.0f;
  for (int t = q*64; t < q*64+64; t++) p += 1.0f - mm[(b*T_ + t)*D_ + d];
  spp[q][d] = p;
  for (int i = tid; i < D_*H_; i += 256){ int r = i >> 7, c = i & 127; sE[r*129+c] = E[i]; }
  __syncthreads();
  if (tid < 64) sp[tid] = (spp[0][tid]+spp[1][tid]+spp[2][tid]+spp[3][tid]) * (1.0f/T_);
  __syncthreads();
  float rowE[128];
  #pragma unroll
  for (int k = 0; k < 128; k++) rowE[k] = sE[d*129+k];
  for (int i = q*16; i < q*16+16; i++){
    float s = 0.0f;
    #pragma unroll
    for (int k = 0; k < 128; k++) s += rowE[k]*sE[i*129+k];
    ssim[d*65+i] = fmaxf(s, 0.0f);
  }
  __syncthreads();
  if (tid < 64){
    float rs = 0.0f;
    for (int j = 0; j < 64; j++) rs += sp[j]*ssim[tid*65+j];
    srs[tid] = fmaxf(sp[tid]*rs + 1.0f, 1e-6f);
  }
  __syncthreads();
  if (tid < 64){
    float s = 0.0f;
    for (int i = 0; i < 64; i++) s += sp[i]*ssim[tid*65+i]/srs[i];
    wcol[b*64 + tid] = sp[tid]*s + 1.0f/srs[tid];
  }
}

// gi_k v6: gi3 f16; E staged into LDS f16 (pitch 132); Phase-B weights/biases
// pre-scaled by LOG2E (r,z rows) / LOG2E2 (n rows) for exp2 gates.
// Phase A: vr[32t][128h] = (x*(1-mm)*wcol/64)[32t][64d] x E[64d][128h] + time-enc
// Phase B: gi[32t][384g] = vr x (sc*W_ih)^T + sc*(bih + bhh[r,z]); gi3 [b][g][t].
#define AVP 72
#define VRP 136
#define SEP 132
__global__ void __launch_bounds__(512,1) gi_k(const float* x, const float* mm,
                                              const float* vt, const float* E,
                                              const float* wih, const float* bih,
                                              const float* bhh, const float* wcol,
                                              _Float16* gi3){
  int bid = blockIdx.x;
  int b = bid >> 3, t0 = (bid & 7)*32;
  int tid = threadIdx.x;
  int w = tid >> 6, l = tid & 63;
  int lq = l >> 4, lm = l & 15;

  __shared__ __align__(16) _Float16 av[32*AVP];
  __shared__ __align__(16) _Float16 vrA[32*VRP];
  __shared__ __align__(16) _Float16 sEl[64*SEP];
  __shared__ float sVt[32];

  // stage av[t][d] = x*(1-mm)*wcol/64  (f32 in, f16 out)
  {
    int i = tid*4, t = i >> 6, d4 = i & 63;
    long src = (long)(b*T_ + t0 + t)*D_ + d4;
    float4 xv = *(const float4*)&x[src];
    float4 mv = *(const float4*)&mm[src];
    float4 wv = *(const float4*)&wcol[b*D_ + d4];
    half4v h;
    h[0]=(_Float16)(xv.x*(1.0f-mv.x)*wv.x*(1.0f/64));
    h[1]=(_Float16)(xv.y*(1.0f-mv.y)*wv.y*(1.0f/64));
    h[2]=(_Float16)(xv.z*(1.0f-mv.z)*wv.z*(1.0f/64));
    h[3]=(_Float16)(xv.w*(1.0f-mv.w)*wv.w*(1.0f/64));
    *(half4v*)&av[t*AVP + d4] = h;
  }
  // stage E -> LDS f16, coalesced
  {
    int r = tid >> 3, c0 = (tid & 7)*16;
    #pragma unroll
    for (int g = 0; g < 4; g++){
      float4 v = *(const float4*)&E[r*H_ + c0 + g*4];
      half4v h;
      h[0]=(_Float16)v.x; h[1]=(_Float16)v.y; h[2]=(_Float16)v.z; h[3]=(_Float16)v.w;
      *(half4v*)&sEl[r*SEP + c0 + g*4] = h;
    }
  }
  if (tid < 32) sVt[tid] = vt[b*T_ + t0 + tid];
  __syncthreads();

  // Phase A B-frags: B[k=d][n] = E[d][16w+n]  (gather from LDS)
  half8 bE[2];
  #pragma unroll
  for (int kc = 0; kc < 2; kc++){
    half8 f;
    #pragma unroll
    for (int jj = 0; jj < 8; jj++)
      f[jj] = sEl[(kc*32 + lq*8 + jj)*SEP + 16*w + lm];
    bE[kc] = f;
  }

  float4v accA[2] = {{0,0,0,0},{0,0,0,0}};
  #pragma unroll
  for (int kc = 0; kc < 2; kc++){
    #pragma unroll
    for (int mt = 0; mt < 2; mt++){
      half8 a = *(const half8*)&av[(mt*16+lm)*AVP + kc*32 + lq*8];
      accA[mt] = __builtin_amdgcn_mfma_f32_16x16x32_f16(a, bE[kc], accA[mt], 0,0,0);
    }
  }
  {
    int h = 16*w + lm;
    float fr = __expf(-(float)(h & 63) * 0.14391157f);   // ln(1e4)/64
    #pragma unroll
    for (int mt = 0; mt < 2; mt++){
      #pragma unroll
      for (int r = 0; r < 4; r++){
        int tl = mt*16 + lq*4 + r;
        float ang = sVt[tl] * fr;
        float e = (h < 64) ? __sinf(ang) : __cosf(ang);
        vrA[tl*VRP + h] = (_Float16)(accA[mt][r] + e);
      }
    }
  }
  __syncthreads();

  // Phase B: wave owns N-tiles 3w..3w+2; weights/bias pre-scaled for exp2 gates
  half8 bW[3][4]; float biW[3];
  #pragma unroll
  for (int q = 0; q < 3; q++){
    int g = 16*(3*w + q) + lm;
    float sc = (g < 2*H_) ? LOG2E : LOG2E2;
    biW[q] = (bih[g] + (g < 2*H_ ? bhh[g] : 0.0f)) * sc;  // fold b_hh for r,z
    #pragma unroll
    for (int kc = 0; kc < 4; kc++){
      const float* src = &wih[(long)g*H_ + kc*32 + lq*8];
      float4 x0 = *(const float4*)src;
      float4 x1 = *(const float4*)(src+4);
      half8 f;
      f[0]=(_Float16)(x0.x*sc); f[1]=(_Float16)(x0.y*sc); f[2]=(_Float16)(x0.z*sc); f[3]=(_Float16)(x0.w*sc);
      f[4]=(_Float16)(x1.x*sc); f[5]=(_Float16)(x1.y*sc); f[6]=(_Float16)(x1.z*sc); f[7]=(_Float16)(x1.w*sc);
      bW[q][kc] = f;
    }
  }
  float4v cB[2][3];
  #pragma unroll
  for (int mt = 0; mt < 2; mt++)
    #pragma unroll
    for (int q = 0; q < 3; q++) cB[mt][q] = (float4v){0,0,0,0};
  #pragma unroll
  for (int kc = 0; kc < 4; kc++){
    #pragma unroll
    for (int mt = 0; mt < 2; mt++){
      half8 a = *(const half8*)&vrA[(mt*16+lm)*VRP + kc*32 + lq*8];
      #pragma unroll
      for (int q = 0; q < 3; q++)
        cB[mt][q] = __builtin_amdgcn_mfma_f32_16x16x32_f16(a, bW[q][kc], cB[mt][q], 0,0,0);
    }
  }
  #pragma unroll
  for (int mt = 0; mt < 2; mt++){
    #pragma unroll
    for (int q = 0; q < 3; q++){
      int g = 16*(3*w + q) + lm;
      int tb = t0 + mt*16 + lq*4;
      half4v hv;
      hv[0]=(_Float16)(cB[mt][q][0] + biW[q]); hv[1]=(_Float16)(cB[mt][q][1] + biW[q]);
      hv[2]=(_Float16)(cB[mt][q][2] + biW[q]); hv[3]=(_Float16)(cB[mt][q][3] + biW[q]);
      *(half4v*)&gi3[((long)(b*G_ + g))*T_ + tb] = hv;
    }
  }
}

// Sequential GRU v21 (R22) = v18 CHAMPION verbatim: 8-wave N-split with
// depth-2 split MFMA chains. Wave w owns gates j in [16w, 16w+16): per
// gate-part (r,z,n) TWO depth-2 chains (a0/a1 -> c*a, a2/a3 -> c*b) summed
// by one VALU add. setprio(1) wraps the MFMA cluster (2 waves/SIMD
// role-stagger). waves_per_eu(2,2) truthful clamp lifts the allocator's
// phantom-occupancy VGPR throttle. Gate math unconditional; LDS h-write +
// out guarded. One LDS-only BAR per step, hb[2] f16 ping-pong, named A/B
// gi prefetch regs.
__global__ void __attribute__((amdgpu_waves_per_eu(2, 2)))
__launch_bounds__(512) gru_k(const _Float16* gi3, const float* whh,
                             const float* bhh, const int* lengths,
                             float* out){
  int b = blockIdx.x;
  int tid = threadIdx.x;
  int w = tid >> 6, l = tid & 63;
  int lq = l >> 4;
  int j = 16*w + (l & 15);       // gate dim owned (valid for all lanes)
  bool gate = (l < 16);
  int len = lengths[b];

  __shared__ __align__(16) _Float16 hb[2][H_];

  // B-frags: q=0 r, 1 z, 2 n ; B[k][n] = sc*W_hh[q*H + 16w + n][k]
  half8 bfrag[3][4];
  #pragma unroll
  for (int q = 0; q < 3; q++){
    int row = q*H_ + 16*w + (l & 15);
    float sc = (q == 2) ? LOG2E2 : LOG2E;
    #pragma unroll
    for (int kc = 0; kc < 4; kc++){
      const float* src = &whh[(long)row*H_ + kc*32 + lq*8];
      float4 x0 = *(const float4*)src;
      float4 x1 = *(const float4*)(src+4);
      half8 f;
      f[0]=(_Float16)(x0.x*sc); f[1]=(_Float16)(x0.y*sc); f[2]=(_Float16)(x0.z*sc); f[3]=(_Float16)(x0.w*sc);
      f[4]=(_Float16)(x1.x*sc); f[5]=(_Float16)(x1.y*sc); f[6]=(_Float16)(x1.z*sc); f[7]=(_Float16)(x1.w*sc);
      bfrag[q][kc] = f;
    }
  }
  float bn_ = bhh[2*H_ + j] * LOG2E2;
  const _Float16* pr = gi3 + ((long)b*G_ + j)*T_;
  const _Float16* pz = pr + (long)H_*T_;
  const _Float16* pn = pr + (long)2*H_*T_;

  if (tid < H_){ hb[0][tid] = (_Float16)0.0f; hb[1][tid] = (_Float16)0.0f; }

  // gi prefetch: named double-buffer registers, static indexing only
  half8 prA, pzA, pnA, prB, pzB, pnB;
  prA = *(const half8*)pr; pzA = *(const half8*)pz; pnA = *(const half8*)pn;
  __syncthreads();   // cold path: full barrier fine

  float hval = 0.0f;

  auto substeps = [&](half8 cr, half8 cz, half8 cn, int c){
    float ho[8];
    #pragma unroll
    for (int i = 0; i < 8; i++){
      const int rp = i & 1;            // read hb[rp], write hb[rp^1]
      half8 a0v = *(const half8*)&hb[rp][ 0 + lq*8];
      half8 a1v = *(const half8*)&hb[rp][32 + lq*8];
      half8 a2v = *(const half8*)&hb[rp][64 + lq*8];
      half8 a3v = *(const half8*)&hb[rp][96 + lq*8];
      float4v c0a = {0,0,0,0}, c1a = {0,0,0,0}, c2a = {0,0,0,0};
      float4v c0b = {0,0,0,0}, c1b = {0,0,0,0}, c2b = {0,0,0,0};
      __builtin_amdgcn_s_setprio(1);
      c0a = __builtin_amdgcn_mfma_f32_16x16x32_f16(a0v, bfrag[0][0], c0a, 0,0,0);
      c1a = __builtin_amdgcn_mfma_f32_16x16x32_f16(a0v, bfrag[1][0], c1a, 0,0,0);
      c2a = __builtin_amdgcn_mfma_f32_16x16x32_f16(a0v, bfrag[2][0], c2a, 0,0,0);
      c0b = __builtin_amdgcn_mfma_f32_16x16x32_f16(a2v, bfrag[0][2], c0b, 0,0,0);
      c1b = __builtin_amdgcn_mfma_f32_16x16x32_f16(a2v, bfrag[1][2], c1b, 0,0,0);
      c2b = __builtin_amdgcn_mfma_f32_16x16x32_f16(a2v, bfrag[2][2], c2b, 0,0,0);
      c0a = __builtin_amdgcn_mfma_f32_16x16x32_f16(a1v, bfrag[0][1], c0a, 0,0,0);
      c1a = __builtin_amdgcn_mfma_f32_16x16x32_f16(a1v, bfrag[1][1], c1a, 0,0,0);
      c2a = __builtin_amdgcn_mfma_f32_16x16x32_f16(a1v, bfrag[2][1], c2a, 0,0,0);
      c0b = __builtin_amdgcn_mfma_f32_16x16x32_f16(a3v, bfrag[0][3], c0b, 0,0,0);
      c1b = __builtin_amdgcn_mfma_f32_16x16x32_f16(a3v, bfrag[1][3], c1b, 0,0,0);
      c2b = __builtin_amdgcn_mfma_f32_16x16x32_f16(a3v, bfrag[2][3], c2b, 0,0,0);
      __builtin_amdgcn_s_setprio(0);
      float ghr = c0a[0] + c0b[0];
      float ghz = c1a[0] + c1b[0];
      float ghn = c2a[0] + c2b[0];
      float r = fsigmoid2((float)cr[i] + ghr);
      float z = fsigmoid2((float)cz[i] + ghz);
      float n = ftanh2((float)cn[i] + r*(ghn + bn_));
      hval = (1.0f - z)*n + z*hval;
      if (gate){
        hb[rp^1][j] = (_Float16)hval;
        ho[i] = (c*8 + i < len) ? hval : 0.0f;
      }
      BAR();
    }
    if (gate){
      long ob = ((long)b*T_ + c*8)*H_ + j;
      #pragma unroll
      for (int i = 0; i < 8; i++) out[ob + (long)i*H_] = ho[i];
    }
  };

  for (int c = 0; c < 32; c += 2){
    {
      int nb = (c+1)*8;
      prB = *(const half8*)(pr+nb); pzB = *(const half8*)(pz+nb); pnB = *(const half8*)(pn+nb);
    }
    substeps(prA, pzA, pnA, c);
    if (c+2 < 32){
      int nb = (c+2)*8;
      prA = *(const half8*)(pr+nb); pzA = *(const half8*)(pz+nb); pnA = *(const half8*)(pn+nb);
    }
    substeps(prB, pzB, pnB, c+1);
  }
}

extern "C" void kernel_launch(void* const* d_in, const int* in_sizes, int n_in,
                              void* d_out, int out_size, void* d_ws, size_t ws_size,
                              hipStream_t stream) {
  char* base = (char*)d_ws;
  size_t off = 0;
  auto alloc = [&](size_t bytes)->void*{
    void* p = base + off; off = (off + bytes + 255) & ~(size_t)255; return p;
  };
  float*     wcol = (float*)alloc((size_t)B_*D_*4);
  _Float16*  gi3  = (_Float16*)alloc((size_t)B_*G_*T_*2);
  if (off > ws_size) return;

  const float* x   = (const float*)d_in[0];
  const float* mm  = (const float*)d_in[1];
  const float* vt  = (const float*)d_in[2];
  const int*   len = (const int*)d_in[4];
  const float* E   = (const float*)d_in[5];
  const float* wih = (const float*)d_in[6];
  const float* whh = (const float*)d_in[7];
  const float* bih = (const float*)d_in[8];
  const float* bhh = (const float*)d_in[9];

  adj_k<<<dim3(B_),dim3(256),0,stream>>>(mm, E, wcol);
  gi_k<<<dim3(256),dim3(512),0,stream>>>(x, mm, vt, E, wih, bih, bhh, wcol, gi3);
  gru_k<<<dim3(B_),dim3(512),0,stream>>>(gi3, whh, bhh, len, (float*)d_out);
}

// Round 12
// 214.272 us; speedup vs baseline: 1.0878x; 1.0691x over previous
//
#include <hip/hip_runtime.h>
#include <hip/hip_bf16.h>

#define B_ 32
#define T_ 256
#define D_ 64
#define H_ 128
#define G_ 384   // 3*H

typedef _Float16 half8 __attribute__((ext_vector_type(8)));
typedef _Float16 half4v __attribute__((ext_vector_type(4)));
typedef float float4v __attribute__((ext_vector_type(4)));
typedef int int8v __attribute__((ext_vector_type(8)));

// Fast gate functions on PRE-SCALED inputs (log2e folded into weights/biases):
// s = log2e * x          -> sigmoid(x) = 1/(1+2^-s)
// t = 2*log2e * x        -> tanh(x)    = 1 - 2/(1+2^t)
__device__ __forceinline__ float fsigmoid2(float s){
  return __builtin_amdgcn_rcpf(1.0f + __builtin_amdgcn_exp2f(-s));
}
__device__ __forceinline__ float ftanh2(float t){
  return 1.0f - 2.0f*__builtin_amdgcn_rcpf(1.0f + __builtin_amdgcn_exp2f(t));
}
#define LOG2E  1.442695041f
#define LOG2E2 2.885390082f

// NOTE (R5-R7 post-mortem): inputs/outputs are f32. bf16 misread was the NaN bug.
//
// Structure ledger (measured):
//  - v10 (R10): 4-wave 1-BAR chained-MFMA = 1241 cyc/step (132.4 us).
//  - v11-v15 (R12-R16): fdot2 line closed (allocator remat/spill; best 139.4).
//  - v16 (R17): rcp/exp2 gates + log2e prefold = 1105 cyc/step (117.9 us).
//  - v17 (R18): 8-wave N-split, 2 waves/SIMD = ~990 cyc/step (105.7 us).
//  - v18 (R19): depth-2 6-chain + setprio + waves_per_eu(2,2) = ~967 cyc/step
//    (103.1 us, VGPR 88) — f16 CHAMPION, reproduced R22 (103.3). Budget:
//    466 MFMA pipe (24/SIMD x 19.4 cyc, invariant in f16) + ~145 ds_read +
//    ~110 gate + ~80 write/BAR + ~165 skew.
//  - v19/v20 (R20/R21): 12-chain split / seeded C-inputs — both REGRESSED
//    (acc-init scales with chain count; VALU-write->MFMA-read hazard).
//  - v22 (R23, this): fp8 K=128 MFMA (mfma_scale_f32_16x16x128_f8f6f4,
//    FMT=fp8, uniform e8m0 scale 2^-4, operands stored x16). 3 MFMA/wave
//    /substep -> 6/SIMD x ~34.6 cyc = ~208 cyc pipe (was 466). No sum tree.
//    k-permutation cancels A-vs-B (both sides use the same lane->k map).
//    RISK: absmax ~0.01-0.03 (fp8 quantization); if fail -> revert v18 and
//    declare the latency floor.
#define BAR() do{ asm volatile("s_waitcnt lgkmcnt(0)" ::: "memory"); \
                  __builtin_amdgcn_s_barrier(); \
                  asm volatile("" ::: "memory"); } while(0)

// wcol[b,j] = column sums of the row-normalized adjacency (R1 derivation):
// adj_raw[i,j] = p_i p_j sim_ij + I; rs_i = 1 + p_i*sum_j p_j sim_ij;
// wcol_j = p_j * sum_i p_i sim_ij / rs_i + 1/rs_j  (sim symmetric).
__global__ void __launch_bounds__(256) adj_k(const float* mm, const float* E,
                                             float* wcol){
  int b = blockIdx.x;
  int tid = threadIdx.x;
  int d = tid & 63, q = tid >> 6;
  __shared__ float spp[4][64];
  __shared__ float sp[64];
  __shared__ float sE[64*129];
  __shared__ float ssim[64*65];
  __shared__ float srs[64];
  float p = 0.0f;
  for (int t = q*64; t < q*64+64; t++) p += 1.0f - mm[(b*T_ + t)*D_ + d];
  spp[q][d] = p;
  for (int i = tid; i < D_*H_; i += 256){ int r = i >> 7, c = i & 127; sE[r*129+c] = E[i]; }
  __syncthreads();
  if (tid < 64) sp[tid] = (spp[0][tid]+spp[1][tid]+spp[2][tid]+spp[3][tid]) * (1.0f/T_);
  __syncthreads();
  float rowE[128];
  #pragma unroll
  for (int k = 0; k < 128; k++) rowE[k] = sE[d*129+k];
  for (int i = q*16; i < q*16+16; i++){
    float s = 0.0f;
    #pragma unroll
    for (int k = 0; k < 128; k++) s += rowE[k]*sE[i*129+k];
    ssim[d*65+i] = fmaxf(s, 0.0f);
  }
  __syncthreads();
  if (tid < 64){
    float rs = 0.0f;
    for (int j = 0; j < 64; j++) rs += sp[j]*ssim[tid*65+j];
    srs[tid] = fmaxf(sp[tid]*rs + 1.0f, 1e-6f);
  }
  __syncthreads();
  if (tid < 64){
    float s = 0.0f;
    for (int i = 0; i < 64; i++) s += sp[i]*ssim[tid*65+i]/srs[i];
    wcol[b*64 + tid] = sp[tid]*s + 1.0f/srs[tid];
  }
}

// gi_k v6: gi3 f16; E staged into LDS f16 (pitch 132); Phase-B weights/biases
// pre-scaled by LOG2E (r,z rows) / LOG2E2 (n rows) for exp2 gates.
// Phase A: vr[32t][128h] = (x*(1-mm)*wcol/64)[32t][64d] x E[64d][128h] + time-enc
// Phase B: gi[32t][384g] = vr x (sc*W_ih)^T + sc*(bih + bhh[r,z]); gi3 [b][g][t].
#define AVP 72
#define VRP 136
#define SEP 132
__global__ void __launch_bounds__(512,1) gi_k(const float* x, const float* mm,
                                              const float* vt, const float* E,
                                              const float* wih, const float* bih,
                                              const float* bhh, const float* wcol,
                                              _Float16* gi3){
  int bid = blockIdx.x;
  int b = bid >> 3, t0 = (bid & 7)*32;
  int tid = threadIdx.x;
  int w = tid >> 6, l = tid & 63;
  int lq = l >> 4, lm = l & 15;

  __shared__ __align__(16) _Float16 av[32*AVP];
  __shared__ __align__(16) _Float16 vrA[32*VRP];
  __shared__ __align__(16) _Float16 sEl[64*SEP];
  __shared__ float sVt[32];

  // stage av[t][d] = x*(1-mm)*wcol/64  (f32 in, f16 out)
  {
    int i = tid*4, t = i >> 6, d4 = i & 63;
    long src = (long)(b*T_ + t0 + t)*D_ + d4;
    float4 xv = *(const float4*)&x[src];
    float4 mv = *(const float4*)&mm[src];
    float4 wv = *(const float4*)&wcol[b*D_ + d4];
    half4v h;
    h[0]=(_Float16)(xv.x*(1.0f-mv.x)*wv.x*(1.0f/64));
    h[1]=(_Float16)(xv.y*(1.0f-mv.y)*wv.y*(1.0f/64));
    h[2]=(_Float16)(xv.z*(1.0f-mv.z)*wv.z*(1.0f/64));
    h[3]=(_Float16)(xv.w*(1.0f-mv.w)*wv.w*(1.0f/64));
    *(half4v*)&av[t*AVP + d4] = h;
  }
  // stage E -> LDS f16, coalesced
  {
    int r = tid >> 3, c0 = (tid & 7)*16;
    #pragma unroll
    for (int g = 0; g < 4; g++){
      float4 v = *(const float4*)&E[r*H_ + c0 + g*4];
      half4v h;
      h[0]=(_Float16)v.x; h[1]=(_Float16)v.y; h[2]=(_Float16)v.z; h[3]=(_Float16)v.w;
      *(half4v*)&sEl[r*SEP + c0 + g*4] = h;
    }
  }
  if (tid < 32) sVt[tid] = vt[b*T_ + t0 + tid];
  __syncthreads();

  // Phase A B-frags: B[k=d][n] = E[d][16w+n]  (gather from LDS)
  half8 bE[2];
  #pragma unroll
  for (int kc = 0; kc < 2; kc++){
    half8 f;
    #pragma unroll
    for (int jj = 0; jj < 8; jj++)
      f[jj] = sEl[(kc*32 + lq*8 + jj)*SEP + 16*w + lm];
    bE[kc] = f;
  }

  float4v accA[2] = {{0,0,0,0},{0,0,0,0}};
  #pragma unroll
  for (int kc = 0; kc < 2; kc++){
    #pragma unroll
    for (int mt = 0; mt < 2; mt++){
      half8 a = *(const half8*)&av[(mt*16+lm)*AVP + kc*32 + lq*8];
      accA[mt] = __builtin_amdgcn_mfma_f32_16x16x32_f16(a, bE[kc], accA[mt], 0,0,0);
    }
  }
  {
    int h = 16*w + lm;
    float fr = __expf(-(float)(h & 63) * 0.14391157f);   // ln(1e4)/64
    #pragma unroll
    for (int mt = 0; mt < 2; mt++){
      #pragma unroll
      for (int r = 0; r < 4; r++){
        int tl = mt*16 + lq*4 + r;
        float ang = sVt[tl] * fr;
        float e = (h < 64) ? __sinf(ang) : __cosf(ang);
        vrA[tl*VRP + h] = (_Float16)(accA[mt][r] + e);
      }
    }
  }
  __syncthreads();

  // Phase B: wave owns N-tiles 3w..3w+2; weights/bias pre-scaled for exp2 gates
  half8 bW[3][4]; float biW[3];
  #pragma unroll
  for (int q = 0; q < 3; q++){
    int g = 16*(3*w + q) + lm;
    float sc = (g < 2*H_) ? LOG2E : LOG2E2;
    biW[q] = (bih[g] + (g < 2*H_ ? bhh[g] : 0.0f)) * sc;  // fold b_hh for r,z
    #pragma unroll
    for (int kc = 0; kc < 4; kc++){
      const float* src = &wih[(long)g*H_ + kc*32 + lq*8];
      float4 x0 = *(const float4*)src;
      float4 x1 = *(const float4*)(src+4);
      half8 f;
      f[0]=(_Float16)(x0.x*sc); f[1]=(_Float16)(x0.y*sc); f[2]=(_Float16)(x0.z*sc); f[3]=(_Float16)(x0.w*sc);
      f[4]=(_Float16)(x1.x*sc); f[5]=(_Float16)(x1.y*sc); f[6]=(_Float16)(x1.z*sc); f[7]=(_Float16)(x1.w*sc);
      bW[q][kc] = f;
    }
  }
  float4v cB[2][3];
  #pragma unroll
  for (int mt = 0; mt < 2; mt++)
    #pragma unroll
    for (int q = 0; q < 3; q++) cB[mt][q] = (float4v){0,0,0,0};
  #pragma unroll
  for (int kc = 0; kc < 4; kc++){
    #pragma unroll
    for (int mt = 0; mt < 2; mt++){
      half8 a = *(const half8*)&vrA[(mt*16+lm)*VRP + kc*32 + lq*8];
      #pragma unroll
      for (int q = 0; q < 3; q++)
        cB[mt][q] = __builtin_amdgcn_mfma_f32_16x16x32_f16(a, bW[q][kc], cB[mt][q], 0,0,0);
    }
  }
  #pragma unroll
  for (int mt = 0; mt < 2; mt++){
    #pragma unroll
    for (int q = 0; q < 3; q++){
      int g = 16*(3*w + q) + lm;
      int tb = t0 + mt*16 + lq*4;
      half4v hv;
      hv[0]=(_Float16)(cB[mt][q][0] + biW[q]); hv[1]=(_Float16)(cB[mt][q][1] + biW[q]);
      hv[2]=(_Float16)(cB[mt][q][2] + biW[q]); hv[3]=(_Float16)(cB[mt][q][3] + biW[q]);
      *(half4v*)&gi3[((long)(b*G_ + g))*T_ + tb] = hv;
    }
  }
}

// Sequential GRU v22 (R23): 8-wave N-split, fp8 K=128 MFMA recurrence.
// Wave w owns gates j in [16w,16w+16). Per substep: ONE
// mfma_scale_f32_16x16x128_f8f6f4 per gate part (r,z,n) — K=128 covered in
// one shot, 3 MFMAs/wave -> 6/SIMD (~208 cyc pipe vs f16's 466). h and W_hh
// quantized to e4m3 STORED x16 with uniform e8m0 scale 2^-4 per operand
// (keeps small values out of subnormals; h is tanh-bounded <=1, W<=0.26).
// Lane (lq,lm): A byte i = h[lq*32+i] (broadcast rows); B byte i =
// W_hh[q*H+16w+lm][lq*32+i] — identical lane->k map on both sides, so any
// HW k-permutation cancels. C extract [0] (col=lane&15, shape-determined).
// Gates stay f32 on f16 gi. Zero-init C (R21 hazard lesson). One LDS-only
// BAR per step, fp8 hb[2][128] ping-pong, named A/B gi prefetch regs.
__global__ void __attribute__((amdgpu_waves_per_eu(2, 2)))
__launch_bounds__(512) gru_k(const _Float16* gi3, const float* whh,
                             const float* bhh, const int* lengths,
                             float* out){
  int b = blockIdx.x;
  int tid = threadIdx.x;
  int w = tid >> 6, l = tid & 63;
  int lq = l >> 4;
  int j = 16*w + (l & 15);       // gate dim owned (valid for all lanes)
  bool gate = (l < 16);
  int len = lengths[b];

  __shared__ __align__(32) unsigned char hb8[2][H_];

  // B-frags (fp8): q=0 r, 1 z, 2 n; byte i of lane (lq,lm) =
  // e4m3(16*sc*W_hh[q*H+16w+lm][lq*32+i])
  int8v bf8[3];
  #pragma unroll
  for (int q = 0; q < 3; q++){
    int row = q*H_ + 16*w + (l & 15);
    float sc16 = ((q == 2) ? LOG2E2 : LOG2E) * 16.0f;
    const float* src = &whh[(long)row*H_ + lq*32];
    int8v f;
    #pragma unroll
    for (int d = 0; d < 8; d++){
      float4 v = *(const float4*)(src + d*4);
      int pk = __builtin_amdgcn_cvt_pk_fp8_f32(v.x*sc16, v.y*sc16, 0, false);
      pk = __builtin_amdgcn_cvt_pk_fp8_f32(v.z*sc16, v.w*sc16, pk, true);
      f[d] = pk;
    }
    bf8[q] = f;
  }
  float bn_ = bhh[2*H_ + j] * LOG2E2;
  const _Float16* pr = gi3 + ((long)b*G_ + j)*T_;
  const _Float16* pz = pr + (long)H_*T_;
  const _Float16* pn = pr + (long)2*H_*T_;

  if (tid < H_){ hb8[0][tid] = 0; hb8[1][tid] = 0; }

  // gi prefetch: named double-buffer registers, static indexing only
  half8 prA, pzA, pnA, prB, pzB, pnB;
  prA = *(const half8*)pr; pzA = *(const half8*)pz; pnA = *(const half8*)pn;
  __syncthreads();   // cold path: full barrier fine

  float hval = 0.0f;

  auto substeps = [&](half8 cr, half8 cz, half8 cn, int c){
    float ho[8];
    #pragma unroll
    for (int i = 0; i < 8; i++){
      const int rp = i & 1;            // read hb8[rp], write hb8[rp^1]
      int8v av = *(const int8v*)&hb8[rp][lq*32];   // 32 B: e4m3(16*h[lq*32..+32])
      float4v c0 = {0,0,0,0}, c1 = {0,0,0,0}, c2 = {0,0,0,0};
      __builtin_amdgcn_s_setprio(1);
      // scale_sel=0, scale=123 (e8m0 2^-4) per operand: (16h)(16w)*2^-8 = h*w
      c0 = __builtin_amdgcn_mfma_scale_f32_16x16x128_f8f6f4(av, bf8[0], c0, 0, 0, 0, 123, 0, 123);
      c1 = __builtin_amdgcn_mfma_scale_f32_16x16x128_f8f6f4(av, bf8[1], c1, 0, 0, 0, 123, 0, 123);
      c2 = __builtin_amdgcn_mfma_scale_f32_16x16x128_f8f6f4(av, bf8[2], c2, 0, 0, 0, 123, 0, 123);
      __builtin_amdgcn_s_setprio(0);
      float r = fsigmoid2((float)cr[i] + c0[0]);
      float z = fsigmoid2((float)cz[i] + c1[0]);
      float n = ftanh2((float)cn[i] + r*(c2[0] + bn_));
      hval = (1.0f - z)*n + z*hval;
      if (gate){
        int hq = __builtin_amdgcn_cvt_pk_fp8_f32(hval*16.0f, hval*16.0f, 0, false);
        hb8[rp^1][j] = (unsigned char)(hq & 0xff);
        ho[i] = (c*8 + i < len) ? hval : 0.0f;
      }
      BAR();
    }
    if (gate){
      long ob = ((long)b*T_ + c*8)*H_ + j;
      #pragma unroll
      for (int i = 0; i < 8; i++) out[ob + (long)i*H_] = ho[i];
    }
  };

  for (int c = 0; c < 32; c += 2){
    {
      int nb = (c+1)*8;
      prB = *(const half8*)(pr+nb); pzB = *(const half8*)(pz+nb); pnB = *(const half8*)(pn+nb);
    }
    substeps(prA, pzA, pnA, c);
    if (c+2 < 32){
      int nb = (c+2)*8;
      prA = *(const half8*)(pr+nb); pzA = *(const half8*)(pz+nb); pnA = *(const half8*)(pn+nb);
    }
    substeps(prB, pzB, pnB, c+1);
  }
}

extern "C" void kernel_launch(void* const* d_in, const int* in_sizes, int n_in,
                              void* d_out, int out_size, void* d_ws, size_t ws_size,
                              hipStream_t stream) {
  char* base = (char*)d_ws;
  size_t off = 0;
  auto alloc = [&](size_t bytes)->void*{
    void* p = base + off; off = (off + bytes + 255) & ~(size_t)255; return p;
  };
  float*     wcol = (float*)alloc((size_t)B_*D_*4);
  _Float16*  gi3  = (_Float16*)alloc((size_t)B_*G_*T_*2);
  if (off > ws_size) return;

  const float* x   = (const float*)d_in[0];
  const float* mm  = (const float*)d_in[1];
  const float* vt  = (const float*)d_in[2];
  const int*   len = (const int*)d_in[4];
  const float* E   = (const float*)d_in[5];
  const float* wih = (const float*)d_in[6];
  const float* whh = (const float*)d_in[7];
  const float* bih = (const float*)d_in[8];
  const float* bhh = (const float*)d_in[9];

  adj_k<<<dim3(B_),dim3(256),0,stream>>>(mm, E, wcol);
  gi_k<<<dim3(256),dim3(512),0,stream>>>(x, mm, vt, E, wih, bih, bhh, wcol, gi3);
  gru_k<<<dim3(B_),dim3(512),0,stream>>>(gi3, whh, bhh, len, (float*)d_out);
}